// Round 3
// baseline (82.789 us; speedup 1.0000x reference)
//
#include <hip/hip_runtime.h>
#include <hip/hip_bf16.h>
#include <math.h>

#define N_ROWS 4096
#define D 512
#define TWO_N 8192
#define NJB2 32              /* 8192 / 256 */
#define NPAIRS2 528          /* 32*33/2 */
#define NKT 8                /* 512 / BK(64) */
#define INV_T 5.0f

typedef __attribute__((ext_vector_type(8))) __bf16 bf16x8;
typedef __attribute__((ext_vector_type(4))) float f32x4;

// ---------------- block reduction helper (broadcasts result) ----------------
template<int K>
__device__ inline void block_reduce_bcast(float (&v)[K]) {
  __shared__ float red[4][K];
  const int t = threadIdx.x;
  #pragma unroll
  for (int off = 32; off; off >>= 1)
    #pragma unroll
    for (int i = 0; i < K; ++i) v[i] += __shfl_xor(v[i], off, 64);
  __syncthreads();
  if ((t & 63) == 0)
    #pragma unroll
    for (int i = 0; i < K; ++i) red[t >> 6][i] = v[i];
  __syncthreads();
  #pragma unroll
  for (int i = 0; i < K; ++i) v[i] = red[0][i] + red[1][i] + red[2][i] + red[3][i];
}

// ---------------- kernel 1: normalize rows, emit bf16 reps + fp32 stats ----
__global__ __launch_bounds__(256) void normalize_kernel(
    const float* __restrict__ ei_, const float* __restrict__ ej_,
    const float* __restrict__ ek_,
    __hip_bfloat16* __restrict__ reps, float* __restrict__ diagexp,
    float* __restrict__ pos_ij, float* __restrict__ exp_ik)
{
  const int n = blockIdx.x;
  const int t = threadIdx.x;
  const long base = (long)n * D + 2 * t;
  const float2 ei = *reinterpret_cast<const float2*>(ei_ + base);
  const float2 ej = *reinterpret_cast<const float2*>(ej_ + base);
  const float2 ek = *reinterpret_cast<const float2*>(ek_ + base);

  float v[5];
  v[0] = ei.x * ei.x + ei.y * ei.y;
  v[1] = ej.x * ej.x + ej.y * ej.y;
  v[2] = ek.x * ek.x + ek.y * ek.y;
  v[3] = ei.x * ej.x + ei.y * ej.y;
  v[4] = ek.x * ei.x + ek.y * ei.y;
  block_reduce_bcast<5>(v);

  const float ni = fmaxf(sqrtf(v[0]), 1e-12f);
  const float nj = fmaxf(sqrtf(v[1]), 1e-12f);
  const float nk = fmaxf(sqrtf(v[2]), 1e-12f);
  const float invi = 1.0f / ni, invj = 1.0f / nj;

  __hip_bfloat162 pi, pj;
  pi.x = __float2bfloat16(ei.x * invi);
  pi.y = __float2bfloat16(ei.y * invi);
  pj.x = __float2bfloat16(ej.x * invj);
  pj.y = __float2bfloat16(ej.y * invj);
  *reinterpret_cast<__hip_bfloat162*>(reps + (long)n * D + 2 * t) = pi;
  *reinterpret_cast<__hip_bfloat162*>(reps + (long)(N_ROWS + n) * D + 2 * t) = pj;

  float q[2];
  {
    float f0 = __bfloat162float(pi.x), f1 = __bfloat162float(pi.y);
    q[0] = f0 * f0 + f1 * f1;
    f0 = __bfloat162float(pj.x); f1 = __bfloat162float(pj.y);
    q[1] = f0 * f0 + f1 * f1;
  }
  block_reduce_bcast<2>(q);

  if (t == 0) {
    diagexp[n]          = __expf(INV_T * q[0]);
    diagexp[N_ROWS + n] = __expf(INV_T * q[1]);
    pos_ij[n] = v[3] / (ni * nj);
    exp_ik[n] = __expf(INV_T * v[4] / (nk * ni));
  }
}

// ---------------- kernel 2: reduce the two scalars --------------------------
__global__ __launch_bounds__(256) void scalar_kernel(
    const float* __restrict__ pos_ij, const float* __restrict__ exp_ik,
    float* __restrict__ scalars)
{
  const int t = threadIdx.x;
  float v[2] = {0.f, 0.f};
  for (int i = t; i < N_ROWS; i += 256) { v[0] += pos_ij[i]; v[1] += exp_ik[i]; }
  block_reduce_bcast<2>(v);
  if (t == 0) { scalars[0] = v[0]; scalars[1] = v[1]; }
}

// ---------------- kernel 3: 256^2 8-phase fused Z*Z^T + exp + row/col sums --
// LDS map (dynamic, 137216 B):
//   A region [0,65536):      [dbuf p][half h][128][64] bf16, XOR-swizzled slots
//   B region [65536,131072): same
//   rowbuf   [131072,135168): float[4][256] (warp_n slots)
//   colbuf   [135168,137216): float[2][256] (warp_m slots)
__device__ __forceinline__ void stage_half(
    const __hip_bfloat16* __restrict__ reps, char* lds_region,
    int R0, int kt_idx, int h, int w, int t)
{
  const int p = kt_idx & 1;
  #pragma unroll
  for (int i = 0; i < 2; ++i) {
    const int row  = i * 64 + (t >> 3);
    const int slot = (t & 7) ^ (row & 7);            // inverse-swizzled source
    const __hip_bfloat16* g =
        reps + (long)(R0 + h * 128 + row) * D + kt_idx * 64 + slot * 8;
    char* lp = lds_region + p * 32768 + h * 16384 + i * 8192 + w * 1024;
    __builtin_amdgcn_global_load_lds(
        (const __attribute__((address_space(1))) void*)g,
        (__attribute__((address_space(3))) void*)lp, 16, 0, 0);
  }
}

__global__ __launch_bounds__(512) void gemm_expsum_kernel256(
    const __hip_bfloat16* __restrict__ reps, float* __restrict__ S_partial)
{
  extern __shared__ __align__(128) char smem[];
  char* Ar = smem;
  char* Br = smem + 65536;
  float* rowbuf = (float*)(smem + 131072);
  float* colbuf = (float*)(smem + 131072 + 4096);

  const int t = threadIdx.x;
  const int l = t & 63;
  const int w = t >> 6;          // wave 0..7
  const int wm = w >> 2;         // warp_m 0..1  (128-row half)
  const int wn = w & 3;          // warp_n 0..3  (64-col span)

  // XCD-aware bijective swizzle (528 = 8*66), then triangular decode I<=J
  const int wg = (blockIdx.x & 7) * 66 + (blockIdx.x >> 3);
  int k = wg, I = 0;
  while (k >= NJB2 - I) { k -= NJB2 - I; ++I; }
  const int J = I + k;
  const int rI = I * 256, cJ = J * 256;

  // fragment LDS byte offsets (excluding dbuf term), T2 swizzle on read
  int a_off[8][2], b_off[4][2];
  #pragma unroll
  for (int mi = 0; mi < 8; ++mi)
    #pragma unroll
    for (int kk = 0; kk < 2; ++kk) {
      const int row = mi * 16 + (l & 15);
      const int slot = kk * 4 + (l >> 4);
      a_off[mi][kk] = wm * 16384 + row * 128 + ((slot ^ (row & 7)) * 16);
    }
  #pragma unroll
  for (int ni = 0; ni < 4; ++ni)
    #pragma unroll
    for (int kk = 0; kk < 2; ++kk) {
      const int r256 = wn * 64 + ni * 16 + (l & 15);
      const int h = r256 >> 7, r = r256 & 127;
      const int slot = kk * 4 + (l >> 4);
      b_off[ni][kk] = h * 16384 + r * 128 + ((slot ^ (r & 7)) * 16);
    }

  f32x4 acc[8][4];
  #pragma unroll
  for (int m = 0; m < 8; ++m)
    #pragma unroll
    for (int n = 0; n < 4; ++n) { f32x4 z = {0.f,0.f,0.f,0.f}; acc[m][n] = z; }
  bf16x8 bfr[2][4];

  // prologue: tile0 A+B, tile1 B; wait tile0 (oldest 8 of 12)
  stage_half(reps, Ar, rI, 0, 0, w, t);
  stage_half(reps, Ar, rI, 0, 1, w, t);
  stage_half(reps, Br, cJ, 0, 0, w, t);
  stage_half(reps, Br, cJ, 0, 1, w, t);
  stage_half(reps, Br, cJ, 1, 0, w, t);
  stage_half(reps, Br, cJ, 1, 1, w, t);
  asm volatile("s_waitcnt vmcnt(4)" ::: "memory");
  __builtin_amdgcn_sched_barrier(0);
  __builtin_amdgcn_s_barrier();

  for (int it = 0; it < 4; ++it) {
    const int a = 2 * it, b = a + 1;
    #pragma unroll
    for (int q8 = 0; q8 < 8; ++q8) {
      const int p  = q8 >> 2;        // dbuf slot of current K-tile (a:0, b:1)
      const int q  = q8 & 3;
      const int kk = q & 1, mh = q >> 1;

      // ds-read this phase's quadrant (current tile landed: vmcnt+bar2 earlier)
      bf16x8 af[4];
      #pragma unroll
      for (int m = 0; m < 4; ++m)
        af[m] = *reinterpret_cast<const bf16x8*>(
            Ar + p * 32768 + a_off[mh * 4 + m][kk]);
      if (q < 2) {
        #pragma unroll
        for (int n = 0; n < 4; ++n)
          bfr[kk][n] = *reinterpret_cast<const bf16x8*>(
              Br + p * 32768 + b_off[n][kk]);
      }

      // prefetch issue table (targets freed exactly one phase earlier)
      if      (q8 == 0) stage_half(reps, Ar, rI, b, 0, w, t);
      else if (q8 == 1) stage_half(reps, Ar, rI, b, 1, w, t);
      else if (q8 == 2) stage_half(reps, Br, cJ, (a + 2) & 7, 0, w, t);
      else if (q8 == 3) stage_half(reps, Br, cJ, (a + 2) & 7, 1, w, t);
      else if (q8 == 4) stage_half(reps, Ar, rI, (a + 2) & 7, 0, w, t);
      else if (q8 == 5) stage_half(reps, Ar, rI, (a + 2) & 7, 1, w, t);
      else if (q8 == 6) stage_half(reps, Br, cJ, (b + 2) & 7, 0, w, t);
      else              stage_half(reps, Br, cJ, (b + 2) & 7, 1, w, t);

      __builtin_amdgcn_s_barrier();
      asm volatile("s_waitcnt lgkmcnt(0)" ::: "memory");
      __builtin_amdgcn_sched_barrier(0);
      __builtin_amdgcn_s_setprio(1);
      #pragma unroll
      for (int m = 0; m < 4; ++m)
        #pragma unroll
        for (int n = 0; n < 4; ++n)
          acc[mh * 4 + m][n] = __builtin_amdgcn_mfma_f32_16x16x32_bf16(
              af[m], bfr[kk][n], acc[mh * 4 + m][n], 0, 0, 0);
      __builtin_amdgcn_s_setprio(0);
      if (q == 3) {   // end of K-tile: next K-tile's A+B = oldest 8 of 12
        asm volatile("s_waitcnt vmcnt(4)" ::: "memory");
        __builtin_amdgcn_sched_barrier(0);
      }
      __builtin_amdgcn_s_barrier();
    }
  }

  // epilogue: e = exp(5*sim); row sums + col sums (symmetry)
  float rsum[8][4];
  float csum[4];
  #pragma unroll
  for (int m = 0; m < 8; ++m)
    #pragma unroll
    for (int j = 0; j < 4; ++j) rsum[m][j] = 0.f;
  #pragma unroll
  for (int n = 0; n < 4; ++n) csum[n] = 0.f;

  #pragma unroll
  for (int m = 0; m < 8; ++m)
    #pragma unroll
    for (int n = 0; n < 4; ++n)
      #pragma unroll
      for (int j = 0; j < 4; ++j) {
        const float e = __expf(INV_T * acc[m][n][j]);
        rsum[m][j] += e;
        csum[n]   += e;
      }

  #pragma unroll
  for (int m = 0; m < 8; ++m) {
    #pragma unroll
    for (int off = 1; off < 16; off <<= 1)
      #pragma unroll
      for (int j = 0; j < 4; ++j) rsum[m][j] += __shfl_xor(rsum[m][j], off, 64);
    if ((l & 15) == 0) {
      const int rloc = wm * 128 + m * 16 + (l >> 4) * 4;
      #pragma unroll
      for (int j = 0; j < 4; ++j) rowbuf[wn * 256 + rloc + j] = rsum[m][j];
    }
  }
  #pragma unroll
  for (int off = 16; off < 64; off <<= 1)
    #pragma unroll
    for (int n = 0; n < 4; ++n) csum[n] += __shfl_xor(csum[n], off, 64);
  if (l < 16) {
    #pragma unroll
    for (int n = 0; n < 4; ++n)
      colbuf[wm * 256 + wn * 64 + n * 16 + l] = csum[n];
  }
  __syncthreads();

  if (t < 256) {
    const float s = rowbuf[t] + rowbuf[256 + t] + rowbuf[512 + t] + rowbuf[768 + t];
    S_partial[(long)J * TWO_N + rI + t] = s;
  } else if (I != J) {
    const int c = t - 256;
    S_partial[(long)I * TWO_N + cJ + c] = colbuf[c] + colbuf[256 + c];
  }
}

// ---------------- kernel 4: per-row log(denominator), block partials -------
__global__ __launch_bounds__(256) void rowlog_kernel(
    const float* __restrict__ S_partial, const float* __restrict__ diagexp,
    const float* __restrict__ scalars, float* __restrict__ blockpart)
{
  const int t = threadIdx.x;
  const int r = blockIdx.x * 256 + t;
  float s = 0.f;
  #pragma unroll 8
  for (int Jb = 0; Jb < NJB2; ++Jb) s += S_partial[(long)Jb * TWO_N + r];
  const float denom_fu = 2.0f * scalars[1];
  float v[1];
  v[0] = logf(s - diagexp[r] + denom_fu);
  block_reduce_bcast<1>(v);
  if (t == 0) blockpart[blockIdx.x] = v[0];
}

// ---------------- kernel 5: final scalar -----------------------------------
__global__ void final_kernel(const float* __restrict__ blockpart,
                             const float* __restrict__ scalars,
                             float* __restrict__ out)
{
  const int t = threadIdx.x;   // 64 threads
  float s = (t < TWO_N / 256) ? blockpart[t] : 0.f;
  #pragma unroll
  for (int off = 32; off; off >>= 1) s += __shfl_xor(s, off, 64);
  if (t == 0) out[0] = (s - 10.0f * scalars[0]) / (float)TWO_N;
}

extern "C" void kernel_launch(void* const* d_in, const int* in_sizes, int n_in,
                              void* d_out, int out_size, void* d_ws, size_t ws_size,
                              hipStream_t stream)
{
  const float* ei = (const float*)d_in[0];
  const float* ej = (const float*)d_in[1];
  const float* ek = (const float*)d_in[2];
  float* out = (float*)d_out;

  char* ws = (char*)d_ws;
  __hip_bfloat16* reps = (__hip_bfloat16*)ws;                          // 8 MB
  float* S_partial = (float*)(ws + 8u * 1024 * 1024);                  // 1 MB
  float* diagexp   = (float*)(ws + 10u * 1024 * 1024);                 // 32 KB
  float* pos_ij    = (float*)(ws + 10u * 1024 * 1024 + 32 * 1024);     // 16 KB
  float* exp_ik    = (float*)(ws + 10u * 1024 * 1024 + 48 * 1024);     // 16 KB
  float* scalars   = (float*)(ws + 10u * 1024 * 1024 + 64 * 1024);     // 8 B
  float* blockpart = (float*)(ws + 10u * 1024 * 1024 + 64 * 1024 + 256); // 128 B

  static const int kSmemBytes = 137216;
  (void)hipFuncSetAttribute((const void*)gemm_expsum_kernel256,
                            hipFuncAttributeMaxDynamicSharedMemorySize,
                            kSmemBytes);

  normalize_kernel<<<N_ROWS, 256, 0, stream>>>(ei, ej, ek, reps, diagexp,
                                               pos_ij, exp_ik);
  scalar_kernel<<<1, 256, 0, stream>>>(pos_ij, exp_ik, scalars);
  gemm_expsum_kernel256<<<NPAIRS2, 512, kSmemBytes, stream>>>(reps, S_partial);
  rowlog_kernel<<<TWO_N / 256, 256, 0, stream>>>(S_partial, diagexp, scalars,
                                                 blockpart);
  final_kernel<<<1, 64, 0, stream>>>(blockpart, scalars, out);
}

// Round 4
// 82.400 us; speedup vs baseline: 1.0047x; 1.0047x over previous
//
#include <hip/hip_runtime.h>
#include <hip/hip_bf16.h>
#include <math.h>

#define N_ROWS 4096
#define D 512
#define TWO_N 8192
#define NJB2 32              /* 8192 / 256 */
#define NPAIRS2 528          /* 32*33/2 */
#define INV_T 5.0f

typedef __attribute__((ext_vector_type(8))) __bf16 bf16x8;
typedef __attribute__((ext_vector_type(4))) float f32x4;

// ---------------- block reduction helper (broadcasts result) ----------------
template<int K>
__device__ inline void block_reduce_bcast(float (&v)[K]) {
  __shared__ float red[4][K];
  const int t = threadIdx.x;
  #pragma unroll
  for (int off = 32; off; off >>= 1)
    #pragma unroll
    for (int i = 0; i < K; ++i) v[i] += __shfl_xor(v[i], off, 64);
  __syncthreads();
  if ((t & 63) == 0)
    #pragma unroll
    for (int i = 0; i < K; ++i) red[t >> 6][i] = v[i];
  __syncthreads();
  #pragma unroll
  for (int i = 0; i < K; ++i) v[i] = red[0][i] + red[1][i] + red[2][i] + red[3][i];
}

// ---------------- kernel 1: normalize rows, emit bf16 reps + fp32 stats ----
__global__ __launch_bounds__(256) void normalize_kernel(
    const float* __restrict__ ei_, const float* __restrict__ ej_,
    const float* __restrict__ ek_,
    __hip_bfloat16* __restrict__ reps, float* __restrict__ diagexp,
    float* __restrict__ pos_ij, float* __restrict__ exp_ik)
{
  const int n = blockIdx.x;
  const int t = threadIdx.x;
  const long base = (long)n * D + 2 * t;
  const float2 ei = *reinterpret_cast<const float2*>(ei_ + base);
  const float2 ej = *reinterpret_cast<const float2*>(ej_ + base);
  const float2 ek = *reinterpret_cast<const float2*>(ek_ + base);

  float v[5];
  v[0] = ei.x * ei.x + ei.y * ei.y;
  v[1] = ej.x * ej.x + ej.y * ej.y;
  v[2] = ek.x * ek.x + ek.y * ek.y;
  v[3] = ei.x * ej.x + ei.y * ej.y;
  v[4] = ek.x * ei.x + ek.y * ei.y;
  block_reduce_bcast<5>(v);

  const float ni = fmaxf(sqrtf(v[0]), 1e-12f);
  const float nj = fmaxf(sqrtf(v[1]), 1e-12f);
  const float nk = fmaxf(sqrtf(v[2]), 1e-12f);
  const float invi = 1.0f / ni, invj = 1.0f / nj;

  __hip_bfloat162 pi, pj;
  pi.x = __float2bfloat16(ei.x * invi);
  pi.y = __float2bfloat16(ei.y * invi);
  pj.x = __float2bfloat16(ej.x * invj);
  pj.y = __float2bfloat16(ej.y * invj);
  *reinterpret_cast<__hip_bfloat162*>(reps + (long)n * D + 2 * t) = pi;
  *reinterpret_cast<__hip_bfloat162*>(reps + (long)(N_ROWS + n) * D + 2 * t) = pj;

  float q[2];
  {
    float f0 = __bfloat162float(pi.x), f1 = __bfloat162float(pi.y);
    q[0] = f0 * f0 + f1 * f1;
    f0 = __bfloat162float(pj.x); f1 = __bfloat162float(pj.y);
    q[1] = f0 * f0 + f1 * f1;
  }
  block_reduce_bcast<2>(q);

  if (t == 0) {
    diagexp[n]          = __expf(INV_T * q[0]);
    diagexp[N_ROWS + n] = __expf(INV_T * q[1]);
    pos_ij[n] = v[3] / (ni * nj);
    exp_ik[n] = __expf(INV_T * v[4] / (nk * ni));
  }
}

// ---------------- kernel 2: reduce the two scalars --------------------------
__global__ __launch_bounds__(256) void scalar_kernel(
    const float* __restrict__ pos_ij, const float* __restrict__ exp_ik,
    float* __restrict__ scalars)
{
  const int t = threadIdx.x;
  float v[2] = {0.f, 0.f};
  for (int i = t; i < N_ROWS; i += 256) { v[0] += pos_ij[i]; v[1] += exp_ik[i]; }
  block_reduce_bcast<2>(v);
  if (t == 0) { scalars[0] = v[0]; scalars[1] = v[1]; }
}

// ---------------- kernel 3: 256^2 8-phase fused Z*Z^T + exp + row/col sums --
// LDS map (dynamic, 137216 B):
//   A region [0,65536):      [dbuf p][half h][128][64] bf16, XOR-swizzled slots
//   B region [65536,131072): same
//   rowbuf   [131072,135168): float[4][256]
//   colbuf   [135168,137216): float[2][256]
__device__ __forceinline__ void stage_half(
    const __hip_bfloat16* __restrict__ reps, char* lds_region,
    int R0, int kt_idx, int h, int w, int t)
{
  const int p = kt_idx & 1;
  #pragma unroll
  for (int i = 0; i < 2; ++i) {
    const int row  = i * 64 + (t >> 3);
    const int slot = (t & 7) ^ (row & 7);            // inverse-swizzled source
    const __hip_bfloat16* g =
        reps + (long)(R0 + h * 128 + row) * D + kt_idx * 64 + slot * 8;
    char* lp = lds_region + p * 32768 + h * 16384 + i * 8192 + w * 1024;
    __builtin_amdgcn_global_load_lds(
        (const __attribute__((address_space(1))) void*)g,
        (__attribute__((address_space(3))) void*)lp, 16, 0, 0);
  }
}

__global__ __launch_bounds__(512) void gemm_expsum_kernel256(
    const __hip_bfloat16* __restrict__ reps, float* __restrict__ S_partial)
{
  extern __shared__ __align__(128) char smem[];
  char* Ar = smem;
  char* Br = smem + 65536;
  float* rowbuf = (float*)(smem + 131072);
  float* colbuf = (float*)(smem + 131072 + 4096);

  const int t = threadIdx.x;
  const int l = t & 63;
  const int w = t >> 6;          // wave 0..7
  const int wm = w >> 2;         // warp_m 0..1  (128-row half)
  const int wn = w & 3;          // warp_n 0..3  (64-col span)

  // XCD-aware bijective swizzle (528 = 8*66), then triangular decode I<=J
  const int wg = (blockIdx.x & 7) * 66 + (blockIdx.x >> 3);
  int k = wg, I = 0;
  while (k >= NJB2 - I) { k -= NJB2 - I; ++I; }
  const int J = I + k;
  const int rI = I * 256, cJ = J * 256;

  // fragment LDS byte offsets (excluding dbuf term), T2 swizzle on read
  int a_off[8][2], b_off[4][2];
  #pragma unroll
  for (int mi = 0; mi < 8; ++mi)
    #pragma unroll
    for (int kk = 0; kk < 2; ++kk) {
      const int row = mi * 16 + (l & 15);
      const int slot = kk * 4 + (l >> 4);
      a_off[mi][kk] = wm * 16384 + row * 128 + ((slot ^ (row & 7)) * 16);
    }
  #pragma unroll
  for (int ni = 0; ni < 4; ++ni)
    #pragma unroll
    for (int kk = 0; kk < 2; ++kk) {
      const int r256 = wn * 64 + ni * 16 + (l & 15);
      const int h = r256 >> 7, r = r256 & 127;
      const int slot = kk * 4 + (l >> 4);
      b_off[ni][kk] = h * 16384 + r * 128 + ((slot ^ (r & 7)) * 16);
    }

  f32x4 acc[8][4];
  #pragma unroll
  for (int m = 0; m < 8; ++m)
    #pragma unroll
    for (int n = 0; n < 4; ++n) { f32x4 z = {0.f,0.f,0.f,0.f}; acc[m][n] = z; }
  bf16x8 bfr[2][4];

  // prologue: tile0 A+B, tile1 B; wait tile0 (oldest 8 of 12)
  stage_half(reps, Ar, rI, 0, 0, w, t);
  stage_half(reps, Ar, rI, 0, 1, w, t);
  stage_half(reps, Br, cJ, 0, 0, w, t);
  stage_half(reps, Br, cJ, 0, 1, w, t);
  stage_half(reps, Br, cJ, 1, 0, w, t);
  stage_half(reps, Br, cJ, 1, 1, w, t);
  asm volatile("s_waitcnt vmcnt(4)" ::: "memory");
  __builtin_amdgcn_s_barrier();

  for (int it = 0; it < 4; ++it) {
    const int a = 2 * it, b = a + 1;
    #pragma unroll
    for (int q8 = 0; q8 < 8; ++q8) {
      const int p  = q8 >> 2;        // dbuf slot of current K-tile (a:0, b:1)
      const int q  = q8 & 3;
      const int kk = q & 1, mh = q >> 1;

      // ds-read this phase's quadrant (plain loads: compiler tracks deps)
      bf16x8 af[4];
      #pragma unroll
      for (int m = 0; m < 4; ++m)
        af[m] = *reinterpret_cast<const bf16x8*>(
            Ar + p * 32768 + a_off[mh * 4 + m][kk]);
      if (q < 2) {
        #pragma unroll
        for (int n = 0; n < 4; ++n)
          bfr[kk][n] = *reinterpret_cast<const bf16x8*>(
              Br + p * 32768 + b_off[n][kk]);
      }

      // prefetch issue table (targets freed exactly one phase earlier)
      if      (q8 == 0) stage_half(reps, Ar, rI, b, 0, w, t);
      else if (q8 == 1) stage_half(reps, Ar, rI, b, 1, w, t);
      else if (q8 == 2) stage_half(reps, Br, cJ, (a + 2) & 7, 0, w, t);
      else if (q8 == 3) stage_half(reps, Br, cJ, (a + 2) & 7, 1, w, t);
      else if (q8 == 4) stage_half(reps, Ar, rI, (a + 2) & 7, 0, w, t);
      else if (q8 == 5) stage_half(reps, Ar, rI, (a + 2) & 7, 1, w, t);
      else if (q8 == 6) stage_half(reps, Br, cJ, (b + 2) & 7, 0, w, t);
      else              stage_half(reps, Br, cJ, (b + 2) & 7, 1, w, t);

      __builtin_amdgcn_s_barrier();
      __builtin_amdgcn_s_setprio(1);
      #pragma unroll
      for (int m = 0; m < 4; ++m)
        #pragma unroll
        for (int n = 0; n < 4; ++n)
          acc[mh * 4 + m][n] = __builtin_amdgcn_mfma_f32_16x16x32_bf16(
              af[m], bfr[kk][n], acc[mh * 4 + m][n], 0, 0, 0);
      __builtin_amdgcn_s_setprio(0);
      if (q == 3) {   // end of K-tile: next K-tile's A+B = oldest 8 of 12
        asm volatile("s_waitcnt vmcnt(4)" ::: "memory");
      }
      __builtin_amdgcn_s_barrier();
    }
  }

  // epilogue: e = exp(5*sim); row sums + col sums (symmetry)
  float rsum[8][4];
  float csum[4];
  #pragma unroll
  for (int m = 0; m < 8; ++m)
    #pragma unroll
    for (int j = 0; j < 4; ++j) rsum[m][j] = 0.f;
  #pragma unroll
  for (int n = 0; n < 4; ++n) csum[n] = 0.f;

  #pragma unroll
  for (int m = 0; m < 8; ++m)
    #pragma unroll
    for (int n = 0; n < 4; ++n)
      #pragma unroll
      for (int j = 0; j < 4; ++j) {
        const float e = __expf(INV_T * acc[m][n][j]);
        rsum[m][j] += e;
        csum[n]   += e;
      }

  #pragma unroll
  for (int m = 0; m < 8; ++m) {
    #pragma unroll
    for (int off = 1; off < 16; off <<= 1)
      #pragma unroll
      for (int j = 0; j < 4; ++j) rsum[m][j] += __shfl_xor(rsum[m][j], off, 64);
    if ((l & 15) == 0) {
      const int rloc = wm * 128 + m * 16 + (l >> 4) * 4;
      #pragma unroll
      for (int j = 0; j < 4; ++j) rowbuf[wn * 256 + rloc + j] = rsum[m][j];
    }
  }
  #pragma unroll
  for (int off = 16; off < 64; off <<= 1)
    #pragma unroll
    for (int n = 0; n < 4; ++n) csum[n] += __shfl_xor(csum[n], off, 64);
  if (l < 16) {
    #pragma unroll
    for (int n = 0; n < 4; ++n)
      colbuf[wm * 256 + wn * 64 + n * 16 + l] = csum[n];
  }
  __syncthreads();

  if (t < 256) {
    const float s = rowbuf[t] + rowbuf[256 + t] + rowbuf[512 + t] + rowbuf[768 + t];
    S_partial[(long)J * TWO_N + rI + t] = s;
  } else if (I != J) {
    const int c = t - 256;
    S_partial[(long)I * TWO_N + cJ + c] = colbuf[c] + colbuf[256 + c];
  }
}

// ---------------- kernel 4: per-row log(denominator), block partials -------
__global__ __launch_bounds__(256) void rowlog_kernel(
    const float* __restrict__ S_partial, const float* __restrict__ diagexp,
    const float* __restrict__ scalars, float* __restrict__ blockpart)
{
  const int t = threadIdx.x;
  const int r = blockIdx.x * 256 + t;
  float s = 0.f;
  #pragma unroll 8
  for (int Jb = 0; Jb < NJB2; ++Jb) s += S_partial[(long)Jb * TWO_N + r];
  const float denom_fu = 2.0f * scalars[1];
  float v[1];
  v[0] = logf(s - diagexp[r] + denom_fu);
  block_reduce_bcast<1>(v);
  if (t == 0) blockpart[blockIdx.x] = v[0];
}

// ---------------- kernel 5: final scalar -----------------------------------
__global__ void final_kernel(const float* __restrict__ blockpart,
                             const float* __restrict__ scalars,
                             float* __restrict__ out)
{
  const int t = threadIdx.x;   // 64 threads
  float s = (t < TWO_N / 256) ? blockpart[t] : 0.f;
  #pragma unroll
  for (int off = 32; off; off >>= 1) s += __shfl_xor(s, off, 64);
  if (t == 0) out[0] = (s - 10.0f * scalars[0]) / (float)TWO_N;
}

extern "C" void kernel_launch(void* const* d_in, const int* in_sizes, int n_in,
                              void* d_out, int out_size, void* d_ws, size_t ws_size,
                              hipStream_t stream)
{
  const float* ei = (const float*)d_in[0];
  const float* ej = (const float*)d_in[1];
  const float* ek = (const float*)d_in[2];
  float* out = (float*)d_out;

  char* ws = (char*)d_ws;
  __hip_bfloat16* reps = (__hip_bfloat16*)ws;                          // 8 MB
  float* S_partial = (float*)(ws + 8u * 1024 * 1024);                  // 1 MB
  float* diagexp   = (float*)(ws + 10u * 1024 * 1024);                 // 32 KB
  float* pos_ij    = (float*)(ws + 10u * 1024 * 1024 + 32 * 1024);     // 16 KB
  float* exp_ik    = (float*)(ws + 10u * 1024 * 1024 + 48 * 1024);     // 16 KB
  float* scalars   = (float*)(ws + 10u * 1024 * 1024 + 64 * 1024);     // 8 B
  float* blockpart = (float*)(ws + 10u * 1024 * 1024 + 64 * 1024 + 256); // 128 B

  static const int kSmemBytes = 137216;
  (void)hipFuncSetAttribute((const void*)gemm_expsum_kernel256,
                            hipFuncAttributeMaxDynamicSharedMemorySize,
                            kSmemBytes);

  normalize_kernel<<<N_ROWS, 256, 0, stream>>>(ei, ej, ek, reps, diagexp,
                                               pos_ij, exp_ik);
  scalar_kernel<<<1, 256, 0, stream>>>(pos_ij, exp_ik, scalars);
  gemm_expsum_kernel256<<<NPAIRS2, 512, kSmemBytes, stream>>>(reps, S_partial);
  rowlog_kernel<<<TWO_N / 256, 256, 0, stream>>>(S_partial, diagexp, scalars,
                                                 blockpart);
  final_kernel<<<1, 64, 0, stream>>>(blockpart, scalars, out);
}

// Round 5
// 82.216 us; speedup vs baseline: 1.0070x; 1.0022x over previous
//
#include <hip/hip_runtime.h>
#include <hip/hip_bf16.h>
#include <math.h>

#define N_ROWS 4096
#define D 512
#define TWO_N 8192
#define NJB2 32              /* 8192 / 256 */
#define NPAIRS2 528          /* 32*33/2 */
#define INV_T 5.0f

typedef __attribute__((ext_vector_type(8))) __bf16 bf16x8;
typedef __attribute__((ext_vector_type(4))) float f32x4;

// ---------------- block reduction helper (broadcasts result) ----------------
template<int K>
__device__ inline void block_reduce_bcast(float (&v)[K]) {
  __shared__ float red[4][K];
  const int t = threadIdx.x;
  #pragma unroll
  for (int off = 32; off; off >>= 1)
    #pragma unroll
    for (int i = 0; i < K; ++i) v[i] += __shfl_xor(v[i], off, 64);
  __syncthreads();
  if ((t & 63) == 0)
    #pragma unroll
    for (int i = 0; i < K; ++i) red[t >> 6][i] = v[i];
  __syncthreads();
  #pragma unroll
  for (int i = 0; i < K; ++i) v[i] = red[0][i] + red[1][i] + red[2][i] + red[3][i];
}

// ---------------- kernel 1: normalize rows, emit bf16 reps + fp32 stats ----
__global__ __launch_bounds__(256) void normalize_kernel(
    const float* __restrict__ ei_, const float* __restrict__ ej_,
    const float* __restrict__ ek_,
    __hip_bfloat16* __restrict__ reps, float* __restrict__ diagexp,
    float* __restrict__ pos_ij, float* __restrict__ exp_ik)
{
  const int n = blockIdx.x;
  const int t = threadIdx.x;
  const long base = (long)n * D + 2 * t;
  const float2 ei = *reinterpret_cast<const float2*>(ei_ + base);
  const float2 ej = *reinterpret_cast<const float2*>(ej_ + base);
  const float2 ek = *reinterpret_cast<const float2*>(ek_ + base);

  float v[5];
  v[0] = ei.x * ei.x + ei.y * ei.y;
  v[1] = ej.x * ej.x + ej.y * ej.y;
  v[2] = ek.x * ek.x + ek.y * ek.y;
  v[3] = ei.x * ej.x + ei.y * ej.y;
  v[4] = ek.x * ei.x + ek.y * ei.y;
  block_reduce_bcast<5>(v);

  const float ni = fmaxf(sqrtf(v[0]), 1e-12f);
  const float nj = fmaxf(sqrtf(v[1]), 1e-12f);
  const float nk = fmaxf(sqrtf(v[2]), 1e-12f);
  const float invi = 1.0f / ni, invj = 1.0f / nj;

  __hip_bfloat162 pi, pj;
  pi.x = __float2bfloat16(ei.x * invi);
  pi.y = __float2bfloat16(ei.y * invi);
  pj.x = __float2bfloat16(ej.x * invj);
  pj.y = __float2bfloat16(ej.y * invj);
  *reinterpret_cast<__hip_bfloat162*>(reps + (long)n * D + 2 * t) = pi;
  *reinterpret_cast<__hip_bfloat162*>(reps + (long)(N_ROWS + n) * D + 2 * t) = pj;

  float q[2];
  {
    float f0 = __bfloat162float(pi.x), f1 = __bfloat162float(pi.y);
    q[0] = f0 * f0 + f1 * f1;
    f0 = __bfloat162float(pj.x); f1 = __bfloat162float(pj.y);
    q[1] = f0 * f0 + f1 * f1;
  }
  block_reduce_bcast<2>(q);

  if (t == 0) {
    diagexp[n]          = __expf(INV_T * q[0]);
    diagexp[N_ROWS + n] = __expf(INV_T * q[1]);
    pos_ij[n] = v[3] / (ni * nj);
    exp_ik[n] = __expf(INV_T * v[4] / (nk * ni));
  }
}

// ---------------- kernel 2: reduce the two scalars --------------------------
__global__ __launch_bounds__(256) void scalar_kernel(
    const float* __restrict__ pos_ij, const float* __restrict__ exp_ik,
    float* __restrict__ scalars)
{
  const int t = threadIdx.x;
  float v[2] = {0.f, 0.f};
  for (int i = t; i < N_ROWS; i += 256) { v[0] += pos_ij[i]; v[1] += exp_ik[i]; }
  block_reduce_bcast<2>(v);
  if (t == 0) { scalars[0] = v[0]; scalars[1] = v[1]; }
}

// ---------------- kernel 3: 256^2, BK=32, 2-phase/K-tile, 2 blocks/CU ------
// LDS map (dynamic, 71680 B):
//   A region [0,32768):      [dbuf p][256][32] bf16, rows 64B, XOR-swz slots
//   B region [32768,65536):  same
//   rowbuf   [65536,69632):  float[4][256]
//   colbuf   [69632,71680):  float[2][256]
// Stage one 8KB half (128 rows x 32 cols) = 1 global_load_lds per thread.
__device__ __forceinline__ void stage32(
    const __hip_bfloat16* __restrict__ reps, char* region,
    int R0, int kt, int h, int t)
{
  const int r_loc = h * 128 + (t >> 2);            // region row 0..255
  const int chunk = (t & 3) ^ ((t >> 3) & 3);      // inverse-swizzled src slot
  const __hip_bfloat16* g = reps + (long)(R0 + r_loc) * D + kt * 32 + chunk * 8;
  char* lp = region + (kt & 1) * 16384 + h * 8192 + t * 16;
  __builtin_amdgcn_global_load_lds(
      (const __attribute__((address_space(1))) void*)g,
      (__attribute__((address_space(3))) void*)lp, 16, 0, 0);
}

__global__ __launch_bounds__(512) void gemm_expsum_kernel256(
    const __hip_bfloat16* __restrict__ reps, float* __restrict__ S_partial)
{
  extern __shared__ __align__(128) char smem[];
  char* Ar = smem;
  char* Br = smem + 32768;
  float* rowbuf = (float*)(smem + 65536);
  float* colbuf = (float*)(smem + 69632);

  const int t = threadIdx.x;
  const int l = t & 63;
  const int w = t >> 6;          // wave 0..7
  const int wm = w >> 2;         // warp_m 0..1  (128-row half)
  const int wn = w & 3;          // warp_n 0..3  (64-col span)

  // XCD-aware bijective swizzle (528 = 8*66), then triangular decode I<=J
  const int wg = (blockIdx.x & 7) * 66 + (blockIdx.x >> 3);
  int k = wg, I = 0;
  while (k >= NJB2 - I) { k -= NJB2 - I; ++I; }
  const int J = I + k;
  const int rI = I * 256, cJ = J * 256;

  // fragment LDS byte offsets (excluding dbuf term); swizzle slot^((r>>1)&3)
  int a_off[8], b_off[4];
  #pragma unroll
  for (int mi = 0; mi < 8; ++mi) {
    const int r = wm * 128 + mi * 16 + (l & 15);
    a_off[mi] = r * 64 + (((l >> 4) ^ ((r >> 1) & 3)) * 16);
  }
  #pragma unroll
  for (int ni = 0; ni < 4; ++ni) {
    const int r = wn * 64 + ni * 16 + (l & 15);
    b_off[ni] = r * 64 + (((l >> 4) ^ ((r >> 1) & 3)) * 16);
  }

  f32x4 acc[8][4];
  #pragma unroll
  for (int m = 0; m < 8; ++m)
    #pragma unroll
    for (int n = 0; n < 4; ++n) { f32x4 z = {0.f,0.f,0.f,0.f}; acc[m][n] = z; }
  bf16x8 bfr[4];

  // prologue: A0, B0, B1 (6 loads); wait A0+B0 (oldest 4 of 6)
  stage32(reps, Ar, rI, 0, 0, t);
  stage32(reps, Ar, rI, 0, 1, t);
  stage32(reps, Br, cJ, 0, 0, t);
  stage32(reps, Br, cJ, 0, 1, t);
  stage32(reps, Br, cJ, 1, 0, t);
  stage32(reps, Br, cJ, 1, 1, t);
  asm volatile("s_waitcnt vmcnt(2)" ::: "memory");
  __builtin_amdgcn_s_barrier();

  for (int it = 0; it < 8; ++it) {
    #pragma unroll
    for (int half = 0; half < 2; ++half) {
      const int m = 2 * it + half;   // K-tile index 0..15
      const int p = half;            // dbuf slot = m&1

      // ---- phase (m,0): read A-frags 0..3 + all B-frags; stage A[m+1] ----
      bf16x8 af0[4];
      #pragma unroll
      for (int mi = 0; mi < 4; ++mi)
        af0[mi] = *reinterpret_cast<const bf16x8*>(Ar + p * 16384 + a_off[mi]);
      #pragma unroll
      for (int n = 0; n < 4; ++n)
        bfr[n] = *reinterpret_cast<const bf16x8*>(Br + p * 16384 + b_off[n]);
      stage32(reps, Ar, rI, (m + 1) & 15, 0, t);
      stage32(reps, Ar, rI, (m + 1) & 15, 1, t);

      __builtin_amdgcn_s_barrier();
      __builtin_amdgcn_s_setprio(1);
      #pragma unroll
      for (int mi = 0; mi < 4; ++mi)
        #pragma unroll
        for (int n = 0; n < 4; ++n)
          acc[mi][n] = __builtin_amdgcn_mfma_f32_16x16x32_bf16(
              af0[mi], bfr[n], acc[mi][n], 0, 0, 0);
      __builtin_amdgcn_s_setprio(0);
      __builtin_amdgcn_s_barrier();

      // ---- phase (m,1): read A-frags 4..7; stage B[m+2]; vmcnt gate ------
      bf16x8 af1[4];
      #pragma unroll
      for (int mi = 0; mi < 4; ++mi)
        af1[mi] = *reinterpret_cast<const bf16x8*>(Ar + p * 16384 + a_off[4 + mi]);
      stage32(reps, Br, cJ, (m + 2) & 15, 0, t);
      stage32(reps, Br, cJ, (m + 2) & 15, 1, t);

      __builtin_amdgcn_s_barrier();
      __builtin_amdgcn_s_setprio(1);
      #pragma unroll
      for (int mi = 0; mi < 4; ++mi)
        #pragma unroll
        for (int n = 0; n < 4; ++n)
          acc[4 + mi][n] = __builtin_amdgcn_mfma_f32_16x16x32_bf16(
              af1[mi], bfr[n], acc[4 + mi][n], 0, 0, 0);
      __builtin_amdgcn_s_setprio(0);
      // next K-tile's A+B are the 4 oldest of 6 outstanding
      asm volatile("s_waitcnt vmcnt(2)" ::: "memory");
      __builtin_amdgcn_s_barrier();
    }
  }

  // epilogue: e = exp(5*sim); row sums + col sums (symmetry)
  float rsum[8][4];
  float csum[4];
  #pragma unroll
  for (int m = 0; m < 8; ++m)
    #pragma unroll
    for (int j = 0; j < 4; ++j) rsum[m][j] = 0.f;
  #pragma unroll
  for (int n = 0; n < 4; ++n) csum[n] = 0.f;

  #pragma unroll
  for (int m = 0; m < 8; ++m)
    #pragma unroll
    for (int n = 0; n < 4; ++n)
      #pragma unroll
      for (int j = 0; j < 4; ++j) {
        const float e = __expf(INV_T * acc[m][n][j]);
        rsum[m][j] += e;
        csum[n]   += e;
      }

  #pragma unroll
  for (int m = 0; m < 8; ++m) {
    #pragma unroll
    for (int off = 1; off < 16; off <<= 1)
      #pragma unroll
      for (int j = 0; j < 4; ++j) rsum[m][j] += __shfl_xor(rsum[m][j], off, 64);
    if ((l & 15) == 0) {
      const int rloc = wm * 128 + m * 16 + (l >> 4) * 4;
      #pragma unroll
      for (int j = 0; j < 4; ++j) rowbuf[wn * 256 + rloc + j] = rsum[m][j];
    }
  }
  #pragma unroll
  for (int off = 16; off < 64; off <<= 1)
    #pragma unroll
    for (int n = 0; n < 4; ++n) csum[n] += __shfl_xor(csum[n], off, 64);
  if (l < 16) {
    #pragma unroll
    for (int n = 0; n < 4; ++n)
      colbuf[wm * 256 + wn * 64 + n * 16 + l] = csum[n];
  }
  __syncthreads();

  if (t < 256) {
    const float s = rowbuf[t] + rowbuf[256 + t] + rowbuf[512 + t] + rowbuf[768 + t];
    S_partial[(long)J * TWO_N + rI + t] = s;
  } else if (I != J) {
    const int c = t - 256;
    S_partial[(long)I * TWO_N + cJ + c] = colbuf[c] + colbuf[256 + c];
  }
}

// ---------------- kernel 4: per-row log(denominator), block partials -------
__global__ __launch_bounds__(256) void rowlog_kernel(
    const float* __restrict__ S_partial, const float* __restrict__ diagexp,
    const float* __restrict__ scalars, float* __restrict__ blockpart)
{
  const int t = threadIdx.x;
  const int r = blockIdx.x * 256 + t;
  float s = 0.f;
  #pragma unroll 8
  for (int Jb = 0; Jb < NJB2; ++Jb) s += S_partial[(long)Jb * TWO_N + r];
  const float denom_fu = 2.0f * scalars[1];
  float v[1];
  v[0] = logf(s - diagexp[r] + denom_fu);
  block_reduce_bcast<1>(v);
  if (t == 0) blockpart[blockIdx.x] = v[0];
}

// ---------------- kernel 5: final scalar -----------------------------------
__global__ void final_kernel(const float* __restrict__ blockpart,
                             const float* __restrict__ scalars,
                             float* __restrict__ out)
{
  const int t = threadIdx.x;   // 64 threads
  float s = (t < TWO_N / 256) ? blockpart[t] : 0.f;
  #pragma unroll
  for (int off = 32; off; off >>= 1) s += __shfl_xor(s, off, 64);
  if (t == 0) out[0] = (s - 10.0f * scalars[0]) / (float)TWO_N;
}

extern "C" void kernel_launch(void* const* d_in, const int* in_sizes, int n_in,
                              void* d_out, int out_size, void* d_ws, size_t ws_size,
                              hipStream_t stream)
{
  const float* ei = (const float*)d_in[0];
  const float* ej = (const float*)d_in[1];
  const float* ek = (const float*)d_in[2];
  float* out = (float*)d_out;

  char* ws = (char*)d_ws;
  __hip_bfloat16* reps = (__hip_bfloat16*)ws;                          // 8 MB
  float* S_partial = (float*)(ws + 8u * 1024 * 1024);                  // 1 MB
  float* diagexp   = (float*)(ws + 10u * 1024 * 1024);                 // 32 KB
  float* pos_ij    = (float*)(ws + 10u * 1024 * 1024 + 32 * 1024);     // 16 KB
  float* exp_ik    = (float*)(ws + 10u * 1024 * 1024 + 48 * 1024);     // 16 KB
  float* scalars   = (float*)(ws + 10u * 1024 * 1024 + 64 * 1024);     // 8 B
  float* blockpart = (float*)(ws + 10u * 1024 * 1024 + 64 * 1024 + 256); // 128 B

  static const int kSmemBytes = 71680;
  (void)hipFuncSetAttribute((const void*)gemm_expsum_kernel256,
                            hipFuncAttributeMaxDynamicSharedMemorySize,
                            kSmemBytes);

  normalize_kernel<<<N_ROWS, 256, 0, stream>>>(ei, ej, ek, reps, diagexp,
                                               pos_ij, exp_ik);
  scalar_kernel<<<1, 256, 0, stream>>>(pos_ij, exp_ik, scalars);
  gemm_expsum_kernel256<<<NPAIRS2, 512, kSmemBytes, stream>>>(reps, S_partial);
  rowlog_kernel<<<TWO_N / 256, 256, 0, stream>>>(S_partial, diagexp, scalars,
                                                 blockpart);
  final_kernel<<<1, 64, 0, stream>>>(blockpart, scalars, out);
}